// Round 2
// baseline (587.568 us; speedup 1.0000x reference)
//
#include <hip/hip_runtime.h>

#define N_ 16
#define V_ 16384
#define D_ 128
#define E_ 65536
#define L_ 2
#define M_ (N_*V_)   // 262144 rows

// Working layout for X/Y is [v][n][d] (v-major). A GEMM "row" is r = v*16+n, so dense
// kernels see a row-major [M][128] matrix, and a 32-row wave tile = exactly 2 vertices.
// That makes the SpMM gather fusible into the GEMM: each wave accumulates its 2 vertices'
// neighbor rows straight into f32 registers shaped like the MFMA A-fragments.

typedef __attribute__((ext_vector_type(8))) short short8;
typedef __attribute__((ext_vector_type(4))) float floatx4;

__device__ inline unsigned short f2bf(float x){
  unsigned u = __builtin_bit_cast(unsigned, x);
  unsigned r = u + 0x7fffu + ((u >> 16) & 1u);
  return (unsigned short)(r >> 16);
}
__device__ inline float bf2f(unsigned short h){
  unsigned u = ((unsigned)h) << 16;
  return __builtin_bit_cast(float, u);
}
__device__ inline unsigned pack2(float a, float b){
  return (unsigned)f2bf(a) | ((unsigned)f2bf(b) << 16);
}

// ---- H [n][v][d] fp32 -> Xb [v][n][d] bf16 (transpose fused into convert) ----
__global__ __launch_bounds__(256) void conv_in_k(const float* __restrict__ H,
                                                 unsigned short* __restrict__ Xb){
  int v = blockIdx.x;
  int t = threadIdx.x;
  int n = t >> 4, dc = t & 15;            // dc: which 8-elem chunk of d
  const float4* h4 = (const float4*)H;
  size_t base = ((size_t)n * V_ + v) * 32 + (size_t)dc * 2;
  float4 a = h4[base], b = h4[base + 1];
  uint4 o;
  o.x = pack2(a.x, a.y);
  o.y = pack2(a.z, a.w);
  o.z = pack2(b.x, b.y);
  o.w = pack2(b.z, b.w);
  ((uint4*)Xb)[(size_t)v * 256 + t] = o;  // contiguous 4KB per v
}

// ---- weights fp32 -> bf16 in MFMA frag-major layout [l][mat][ks][ct][lane][8] ----
__global__ __launch_bounds__(256) void conv_w_k(const float* __restrict__ Wself,
                                                const float* __restrict__ Wnei,
                                                unsigned short* __restrict__ Wb){
  int f = blockIdx.x * 256 + threadIdx.x;          // 0..8191 frags
  int lane = f & 63;
  int ct   = (f >> 6) & 7;
  int ks   = (f >> 9) & 3;
  int mat  = (f >> 11) & 1;
  int l    = (f >> 12) & 1;
  int e = ct * 16 + (lane & 15);
  int d = ks * 32 + (lane >> 4) * 8;
  const float* src = (mat ? Wnei : Wself) + ((size_t)l * D_ * D_ + e * D_ + d);
  uint4 o;
  o.x = pack2(src[0], src[1]);
  o.y = pack2(src[2], src[3]);
  o.z = pack2(src[4], src[5]);
  o.w = pack2(src[6], src[7]);
  ((uint4*)Wb)[f] = o;
}

// ---- CSR build ----
__global__ __launch_bounds__(256) void hist_k(const int* __restrict__ dst, int* __restrict__ cnt){
  int e = blockIdx.x * 256 + threadIdx.x;
  atomicAdd(&cnt[dst[e]], 1);
}

__global__ __launch_bounds__(256) void scan_k(const int* __restrict__ cnt, int* __restrict__ row_ptr){
  __shared__ int part[256];
  int t = threadIdx.x;
  int base = t * 64;
  int s = 0;
  for (int i = 0; i < 64; ++i) s += cnt[base + i];
  part[t] = s;
  __syncthreads();
  for (int d = 1; d < 256; d <<= 1){
    int v = (t >= d) ? part[t - d] : 0;
    __syncthreads();
    part[t] += v;
    __syncthreads();
  }
  int off = part[t] - s;   // exclusive prefix
  for (int i = 0; i < 64; ++i){
    row_ptr[base + i] = off;
    off += cnt[base + i];
  }
  if (t == 255) row_ptr[V_] = off;
}

__global__ __launch_bounds__(256) void scatter_k(const int* __restrict__ src,
                                                 const int* __restrict__ dst,
                                                 const float* __restrict__ vals,
                                                 const int* __restrict__ row_ptr,
                                                 int* __restrict__ fill,
                                                 int* __restrict__ csr_col,
                                                 float* __restrict__ csr_val){
  int e = blockIdx.x * 256 + threadIdx.x;
  int d = dst[e];
  int pos = row_ptr[d] + atomicAdd(&fill[d], 1);
  csr_col[pos] = src[e];
  csr_val[pos] = vals[e];
}

// ---- Fused SpMM + GEMM: Y = Xsrc*Ws^T + (A @ Xsrc)*Wn^T (bf16 MFMA)
//      -> Y bf16 + fused BN partial stats (LDS-reduced, 256 atomics/block).
//      NORM: Xsrc holds raw prev-layer Y; apply relu(x*sc+sh) to both self frags
//      and gathered neighbor rows (identical numerics to the unfused version). ----
template<int NORM>
__global__ __launch_bounds__(256, 2) void gemm_k(const unsigned short* __restrict__ X,
                                                 const uint4* __restrict__ Wfrag,
                                                 const float* __restrict__ scsh,
                                                 const int* __restrict__ row_ptr,
                                                 const int* __restrict__ csr_col,
                                                 const float* __restrict__ csr_val,
                                                 unsigned short* __restrict__ Yb,
                                                 float* __restrict__ stats){
  __shared__ uint4 lds_w[4096];                     // 64 KB: [mat][ks][ct][lane]
  __shared__ float lds_s[256];
  __shared__ float lds_red[4 * 256];                // per-wave stats slab
  int tid = threadIdx.x;
  for (int i = tid; i < 4096; i += 256) lds_w[i] = Wfrag[i];
  if (NORM) lds_s[tid] = scsh[tid];
  __syncthreads();

  int wave = tid >> 6, lane = tid & 63;
  int quad = lane >> 4, l15 = lane & 15;
  int row0 = blockIdx.x * 128 + wave * 32;
  int v0 = row0 >> 4;                               // wave owns vertices v0, v0+1

  // ---- fused gather: Xnei rows accumulated directly into A-frag-shaped f32 regs ----
  float accn[2][4][8];
#pragma unroll
  for (int rt = 0; rt < 2; ++rt)
#pragma unroll
    for (int ks = 0; ks < 4; ++ks)
#pragma unroll
      for (int j = 0; j < 8; ++j) accn[rt][ks][j] = 0.f;

#pragma unroll
  for (int rt = 0; rt < 2; ++rt){
    int v = v0 + rt;
    int r0 = row_ptr[v], r1 = row_ptr[v + 1];
#pragma unroll
    for (int ks = 0; ks < 4; ++ks){
      float scv[8], shv[8];
      if (NORM){
        int cb = ks * 32 + quad * 8;
#pragma unroll
        for (int j = 0; j < 8; ++j){
          scv[j] = lds_s[cb + j];
          shv[j] = lds_s[128 + cb + j];
        }
      }
      for (int i = r0; i < r1; ++i){
        int c = csr_col[i];                         // wave-uniform -> scalar load
        float a = csr_val[i];
        short8 w = *(const short8*)(X + ((size_t)c * 16 + l15) * 128 + ks * 32 + quad * 8);
#pragma unroll
        for (int j = 0; j < 8; ++j){
          float x = bf2f((unsigned short)w[j]);
          if (NORM) x = fmaxf(0.f, x * scv[j] + shv[j]);
          accn[rt][ks][j] += a * x;
        }
      }
    }
  }
  // convert to bf16 A-frags (same rounding as the old Xnei materialization)
  short8 a_n[2][4];
#pragma unroll
  for (int rt = 0; rt < 2; ++rt)
#pragma unroll
    for (int ks = 0; ks < 4; ++ks)
#pragma unroll
      for (int j = 0; j < 8; ++j) a_n[rt][ks][j] = (short)f2bf(accn[rt][ks][j]);

  floatx4 zero = {0.f, 0.f, 0.f, 0.f};
  floatx4 acc[2][8];
#pragma unroll
  for (int rt = 0; rt < 2; ++rt)
#pragma unroll
    for (int ct = 0; ct < 8; ++ct) acc[rt][ct] = zero;

  const short8* lw = (const short8*)lds_w;
#pragma unroll
  for (int ks = 0; ks < 4; ++ks){
    float scv[8], shv[8];
    if (NORM){
      int cb = ks * 32 + quad * 8;
#pragma unroll
      for (int j = 0; j < 8; ++j){
        scv[j] = lds_s[cb + j];
        shv[j] = lds_s[128 + cb + j];
      }
    }
    short8 a_s[2];
#pragma unroll
    for (int rt = 0; rt < 2; ++rt){
      size_t r = (size_t)(row0 + rt * 16 + l15);
      short8 raw = *(const short8*)(X + r * 128 + ks * 32 + quad * 8);
      if (NORM){
        short8 t;
#pragma unroll
        for (int j = 0; j < 8; ++j){
          float x = bf2f((unsigned short)raw[j]);
          x = fmaxf(0.f, x * scv[j] + shv[j]);
          t[j] = (short)f2bf(x);
        }
        a_s[rt] = t;
      } else {
        a_s[rt] = raw;
      }
    }
#pragma unroll
    for (int ct = 0; ct < 8; ++ct){
      short8 bs = lw[((0 * 4 + ks) * 8 + ct) * 64 + lane];
      short8 bn = lw[((1 * 4 + ks) * 8 + ct) * 64 + lane];
#pragma unroll
      for (int rt = 0; rt < 2; ++rt){
        acc[rt][ct] = __builtin_amdgcn_mfma_f32_16x16x32_bf16(a_s[rt], bs, acc[rt][ct], 0, 0, 0);
        acc[rt][ct] = __builtin_amdgcn_mfma_f32_16x16x32_bf16(a_n[rt][ks], bn, acc[rt][ct], 0, 0, 0);
      }
    }
  }

  // epilogue: bf16 Y store (C layout: col=lane&15, row=quad*4+reg) + per-wave LDS stats
  float* wred = lds_red + wave * 256;
#pragma unroll
  for (int rt = 0; rt < 2; ++rt){
    int rowq = row0 + rt * 16 + quad * 4;
#pragma unroll
    for (int ct = 0; ct < 8; ++ct){
      int col = ct * 16 + l15;
      float s = 0.f, q = 0.f;
#pragma unroll
      for (int rg = 0; rg < 4; ++rg){
        float yv = acc[rt][ct][rg];
        Yb[(size_t)(rowq + rg) * 128 + col] = f2bf(yv);
        s += yv; q += yv * yv;
      }
      s += __shfl_xor(s, 16); s += __shfl_xor(s, 32);
      q += __shfl_xor(q, 16); q += __shfl_xor(q, 32);
      if (lane < 16){
        if (rt == 0) wred[ct * 16 + lane] = s; else wred[ct * 16 + lane] += s;
      } else if (lane < 32){
        int c2 = ct * 16 + (lane & 15);
        if (rt == 0) wred[128 + c2] = q; else wred[128 + c2] += q;
      }
    }
  }
  __syncthreads();
  // cross-wave reduce -> 256 global atomics per block (was 2048)
  {
    float tot = lds_red[tid] + lds_red[256 + tid] + lds_red[512 + tid] + lds_red[768 + tid];
    int col = tid & 127;
    int slot = blockIdx.x & 63;
    float* dstp = (tid < 128) ? (stats + slot * 128 + col)
                              : (stats + 64 * 128 + slot * 128 + col);
    atomicAdd(dstp, tot);
  }
}

// ---- reduce stats -> scale/shift ----
__global__ __launch_bounds__(128) void finalize_k(const float* __restrict__ stats,
                                                  const float* __restrict__ gamma,
                                                  const float* __restrict__ beta,
                                                  float* __restrict__ scsh){
  int d = threadIdx.x;
  float s = 0.f, q = 0.f;
  for (int k = 0; k < 64; ++k){
    s += stats[k * 128 + d];
    q += stats[64 * 128 + k * 128 + d];
  }
  float inv = 1.0f / (float)M_;
  float mean = s * inv;
  float var  = q * inv - mean * mean;
  float rstd = rsqrtf(var + 1e-5f);
  float scale = gamma[d] * rstd;
  scsh[d]       = scale;
  scsh[128 + d] = beta[d] - mean * scale;
}

// ---- final BN apply + ReLU: Y [v][n][d] bf16 -> out [n][v][d] fp32 (transpose back) ----
__global__ __launch_bounds__(256) void bn_out_k(const uint4* __restrict__ Y,
                                                const float* __restrict__ scsh,
                                                float4* __restrict__ out){
  int v = blockIdx.x;
  int t = threadIdx.x;
  int n = t >> 4, dc = t & 15;
  uint4 y = Y[(size_t)v * 256 + t];
  int d0 = dc * 8;
  float4 sc0 = *(const float4*)(scsh + d0);
  float4 sc1 = *(const float4*)(scsh + d0 + 4);
  float4 sh0 = *(const float4*)(scsh + 128 + d0);
  float4 sh1 = *(const float4*)(scsh + 128 + d0 + 4);
  float4 o0, o1;
  o0.x = fmaxf(0.f, bf2f((unsigned short)(y.x & 0xffff)) * sc0.x + sh0.x);
  o0.y = fmaxf(0.f, bf2f((unsigned short)(y.x >> 16))    * sc0.y + sh0.y);
  o0.z = fmaxf(0.f, bf2f((unsigned short)(y.y & 0xffff)) * sc0.z + sh0.z);
  o0.w = fmaxf(0.f, bf2f((unsigned short)(y.y >> 16))    * sc0.w + sh0.w);
  o1.x = fmaxf(0.f, bf2f((unsigned short)(y.z & 0xffff)) * sc1.x + sh1.x);
  o1.y = fmaxf(0.f, bf2f((unsigned short)(y.z >> 16))    * sc1.y + sh1.y);
  o1.z = fmaxf(0.f, bf2f((unsigned short)(y.w & 0xffff)) * sc1.z + sh1.z);
  o1.w = fmaxf(0.f, bf2f((unsigned short)(y.w >> 16))    * sc1.w + sh1.w);
  size_t ob = ((size_t)n * V_ + v) * 32 + (size_t)dc * 2;
  out[ob]     = o0;
  out[ob + 1] = o1;
}

static inline size_t align_up(size_t x, size_t a){ return (x + a - 1) & ~(a - 1); }

extern "C" void kernel_launch(void* const* d_in, const int* in_sizes, int n_in,
                              void* d_out, int out_size, void* d_ws, size_t ws_size,
                              hipStream_t stream){
  const float* H     = (const float*)d_in[0];
  const int*   esrc  = (const int*)  d_in[1];
  const int*   edst  = (const int*)  d_in[2];
  const float* avals = (const float*)d_in[3];
  const float* Wself = (const float*)d_in[4];
  const float* Wnei  = (const float*)d_in[5];
  const float* gamma = (const float*)d_in[6];
  const float* beta  = (const float*)d_in[7];

  char* ws = (char*)d_ws;
  size_t off = 0;
  unsigned short* Xb   = (unsigned short*)(ws + off); off += align_up((size_t)M_ * D_ * 2, 256);
  unsigned short* Y0   = (unsigned short*)(ws + off); off += align_up((size_t)M_ * D_ * 2, 256);
  unsigned short* Wb   = (unsigned short*)(ws + off); off += align_up((size_t)L_ * 2 * D_ * D_ * 2, 256);
  int*   row_ptr = (int*)  (ws + off); off += align_up((size_t)(V_ + 1) * 4, 256);
  int*   csr_col = (int*)  (ws + off); off += align_up((size_t)E_ * 4, 256);
  float* csr_val = (float*)(ws + off); off += align_up((size_t)E_ * 4, 256);
  float* scsh0   = (float*)(ws + off); off += align_up((size_t)2 * 128 * 4, 256);
  float* scsh1   = (float*)(ws + off); off += align_up((size_t)2 * 128 * 4, 256);
  // contiguous zeroed region: cnt | fill | stats0 | stats1
  char* zbase = ws + off;
  int*   cnt    = (int*)  (ws + off); off += (size_t)V_ * 4;
  int*   fill   = (int*)  (ws + off); off += (size_t)V_ * 4;
  float* stats0 = (float*)(ws + off); off += (size_t)64 * 128 * 2 * 4;
  float* stats1 = (float*)(ws + off); off += (size_t)64 * 128 * 2 * 4;
  size_t zbytes = (size_t)(ws + off - zbase);
  unsigned short* Y1 = Xb;   // Xb is dead after gemm<0> reads it
  (void)ws_size; (void)in_sizes; (void)n_in; (void)out_size;

  conv_in_k<<<V_, 256, 0, stream>>>(H, Xb);
  conv_w_k<<<8192 / 256, 256, 0, stream>>>(Wself, Wnei, Wb);
  hipMemsetAsync(zbase, 0, zbytes, stream);
  hist_k<<<E_ / 256, 256, 0, stream>>>(edst, cnt);
  scan_k<<<1, 256, 0, stream>>>(cnt, row_ptr);
  scatter_k<<<E_ / 256, 256, 0, stream>>>(esrc, edst, avals, row_ptr, fill, csr_col, csr_val);

  // ---- layer 0 (SpMM fused into GEMM) ----
  gemm_k<0><<<M_ / 128, 256, 0, stream>>>(Xb, (const uint4*)Wb, nullptr,
                                          row_ptr, csr_col, csr_val, Y0, stats0);
  finalize_k<<<1, 128, 0, stream>>>(stats0, gamma, beta, scsh0);

  // ---- layer 1 (BN+ReLU of layer 0 fused into consumers) ----
  gemm_k<1><<<M_ / 128, 256, 0, stream>>>(Y0, (const uint4*)Wb + 4096, scsh0,
                                          row_ptr, csr_col, csr_val, Y1, stats1);
  finalize_k<<<1, 128, 0, stream>>>(stats1, gamma + 128, beta + 128, scsh1);
  bn_out_k<<<V_, 256, 0, stream>>>((const uint4*)Y1, scsh1, (float4*)d_out);
}

// Round 4
// 500.189 us; speedup vs baseline: 1.1747x; 1.1747x over previous
//
#include <hip/hip_runtime.h>

#define N_ 16
#define V_ 16384
#define D_ 128
#define E_ 65536
#define L_ 2
#define M_ (N_*V_)   // 262144 rows

// Working layout for X/Y is [v][n][d] (v-major). A GEMM "row" is r = v*16+n, so dense
// kernels see a row-major [M][128] matrix, and a 32-row wave tile = exactly 2 vertices.
// SpMM is fused into the GEMM: each wave gathers its 2 vertices' neighbor rows with an
// edge-OUTER loop (4 independent 16B loads per edge = MLP 4+, next-edge col/val
// prefetched) straight into f32 regs shaped like MFMA A-fragments.
// BN+ReLU between layers is a separate cheap streaming pass (bn_mid_k) so the hot
// gemm has no NORM work at all.

typedef __attribute__((ext_vector_type(8))) short short8;
typedef __attribute__((ext_vector_type(4))) float floatx4;

__device__ inline unsigned short f2bf(float x){
  unsigned u = __builtin_bit_cast(unsigned, x);
  unsigned r = u + 0x7fffu + ((u >> 16) & 1u);
  return (unsigned short)(r >> 16);
}
__device__ inline float bf2f(unsigned short h){
  unsigned u = ((unsigned)h) << 16;
  return __builtin_bit_cast(float, u);
}
__device__ inline unsigned pack2(float a, float b){
  return (unsigned)f2bf(a) | ((unsigned)f2bf(b) << 16);
}

// ---- H [n][v][d] fp32 -> Xb [v][n][d] bf16 (transpose fused into convert) ----
__global__ __launch_bounds__(256) void conv_in_k(const float* __restrict__ H,
                                                 unsigned short* __restrict__ Xb){
  int v = blockIdx.x;
  int t = threadIdx.x;
  int n = t >> 4, dc = t & 15;            // dc: which 8-elem chunk of d
  const float4* h4 = (const float4*)H;
  size_t base = ((size_t)n * V_ + v) * 32 + (size_t)dc * 2;
  float4 a = h4[base], b = h4[base + 1];
  uint4 o;
  o.x = pack2(a.x, a.y);
  o.y = pack2(a.z, a.w);
  o.z = pack2(b.x, b.y);
  o.w = pack2(b.z, b.w);
  ((uint4*)Xb)[(size_t)v * 256 + t] = o;  // contiguous 4KB per v
}

// ---- weights fp32 -> bf16 in MFMA frag-major layout [l][mat][ks][ct][lane][8] ----
__global__ __launch_bounds__(256) void conv_w_k(const float* __restrict__ Wself,
                                                const float* __restrict__ Wnei,
                                                unsigned short* __restrict__ Wb){
  int f = blockIdx.x * 256 + threadIdx.x;          // 0..8191 frags
  int lane = f & 63;
  int ct   = (f >> 6) & 7;
  int ks   = (f >> 9) & 3;
  int mat  = (f >> 11) & 1;
  int l    = (f >> 12) & 1;
  int e = ct * 16 + (lane & 15);
  int d = ks * 32 + (lane >> 4) * 8;
  const float* src = (mat ? Wnei : Wself) + ((size_t)l * D_ * D_ + e * D_ + d);
  uint4 o;
  o.x = pack2(src[0], src[1]);
  o.y = pack2(src[2], src[3]);
  o.z = pack2(src[4], src[5]);
  o.w = pack2(src[6], src[7]);
  ((uint4*)Wb)[f] = o;
}

// ---- CSR build ----
__global__ __launch_bounds__(256) void hist_k(const int* __restrict__ dst, int* __restrict__ cnt){
  int e = blockIdx.x * 256 + threadIdx.x;
  atomicAdd(&cnt[dst[e]], 1);
}

__global__ __launch_bounds__(256) void scan_k(const int* __restrict__ cnt, int* __restrict__ row_ptr){
  __shared__ int part[256];
  int t = threadIdx.x;
  int base = t * 64;
  int s = 0;
  for (int i = 0; i < 64; ++i) s += cnt[base + i];
  part[t] = s;
  __syncthreads();
  for (int d = 1; d < 256; d <<= 1){
    int v = (t >= d) ? part[t - d] : 0;
    __syncthreads();
    part[t] += v;
    __syncthreads();
  }
  int off = part[t] - s;   // exclusive prefix
  for (int i = 0; i < 64; ++i){
    row_ptr[base + i] = off;
    off += cnt[base + i];
  }
  if (t == 255) row_ptr[V_] = off;
}

__global__ __launch_bounds__(256) void scatter_k(const int* __restrict__ src,
                                                 const int* __restrict__ dst,
                                                 const float* __restrict__ vals,
                                                 const int* __restrict__ row_ptr,
                                                 int* __restrict__ fill,
                                                 int* __restrict__ csr_col,
                                                 float* __restrict__ csr_val){
  int e = blockIdx.x * 256 + threadIdx.x;
  int d = dst[e];
  int pos = row_ptr[d] + atomicAdd(&fill[d], 1);
  csr_col[pos] = src[e];
  csr_val[pos] = vals[e];
}

// ---- Fused SpMM + GEMM (no NORM): Y = X*Ws^T + (A @ X)*Wn^T (bf16 MFMA)
//      -> Y bf16 + fused BN partial stats (LDS-reduced, 256 atomics/block). ----
__global__ __launch_bounds__(256, 2) void gemm_k(const unsigned short* __restrict__ X,
                                                 const uint4* __restrict__ Wfrag,
                                                 const int* __restrict__ row_ptr,
                                                 const int* __restrict__ csr_col,
                                                 const float* __restrict__ csr_val,
                                                 unsigned short* __restrict__ Yb,
                                                 float* __restrict__ stats){
  __shared__ uint4 lds_w[4096];                     // 64 KB: [mat][ks][ct][lane]
  __shared__ float lds_red[4 * 256];                // per-wave stats slab
  int tid = threadIdx.x;
  for (int i = tid; i < 4096; i += 256) lds_w[i] = Wfrag[i];   // barrier deferred to post-gather

  int wave = tid >> 6, lane = tid & 63;
  int quad = lane >> 4, l15 = lane & 15;
  int row0 = blockIdx.x * 128 + wave * 32;
  int v0 = row0 >> 4;                               // wave owns vertices v0, v0+1

  // hoist self-row A-frags (8 independent loads, in flight during gather)
  short8 a_s[2][4];
#pragma unroll
  for (int rt = 0; rt < 2; ++rt)
#pragma unroll
    for (int ks = 0; ks < 4; ++ks)
      a_s[rt][ks] = *(const short8*)(X + (size_t)(row0 + rt * 16 + l15) * 128 + ks * 32 + quad * 8);

  // hoist row_ptr (3 loads)
  int r0a = row_ptr[v0], r1a = row_ptr[v0 + 1], r1b = row_ptr[v0 + 2];

  // ---- fused gather, edge-outer: per edge 4 independent 16B loads + (c,a) prefetch ----
  float accn[2][4][8];
#pragma unroll
  for (int rt = 0; rt < 2; ++rt)
#pragma unroll
    for (int ks = 0; ks < 4; ++ks)
#pragma unroll
      for (int j = 0; j < 8; ++j) accn[rt][ks][j] = 0.f;

#pragma unroll
  for (int rt = 0; rt < 2; ++rt){
    int r0 = rt ? r1a : r0a;
    int r1 = rt ? r1b : r1a;
    if (r0 < r1){
      int c = csr_col[r0];
      float a = csr_val[r0];
      for (int i = r0; i < r1; ++i){
        int ip = (i + 1 < r1) ? i + 1 : i;
        int cn = csr_col[ip];
        float an = csr_val[ip];
        const unsigned short* rp = X + ((size_t)c * 16 + l15) * 128 + quad * 8;
        short8 w0 = *(const short8*)(rp);
        short8 w1 = *(const short8*)(rp + 32);
        short8 w2 = *(const short8*)(rp + 64);
        short8 w3 = *(const short8*)(rp + 96);
#pragma unroll
        for (int j = 0; j < 8; ++j) accn[rt][0][j] += a * bf2f((unsigned short)w0[j]);
#pragma unroll
        for (int j = 0; j < 8; ++j) accn[rt][1][j] += a * bf2f((unsigned short)w1[j]);
#pragma unroll
        for (int j = 0; j < 8; ++j) accn[rt][2][j] += a * bf2f((unsigned short)w2[j]);
#pragma unroll
        for (int j = 0; j < 8; ++j) accn[rt][3][j] += a * bf2f((unsigned short)w3[j]);
        c = cn; a = an;
      }
    }
  }
  // convert to bf16 A-frags (same per-(ks,j) edge-order summation as before)
  short8 a_n[2][4];
#pragma unroll
  for (int rt = 0; rt < 2; ++rt)
#pragma unroll
    for (int ks = 0; ks < 4; ++ks)
#pragma unroll
      for (int j = 0; j < 8; ++j) a_n[rt][ks][j] = (short)f2bf(accn[rt][ks][j]);

  __syncthreads();                                  // weights staged (overlapped with gather)

  floatx4 zero = {0.f, 0.f, 0.f, 0.f};
  floatx4 acc[2][8];
#pragma unroll
  for (int rt = 0; rt < 2; ++rt)
#pragma unroll
    for (int ct = 0; ct < 8; ++ct) acc[rt][ct] = zero;

  const short8* lw = (const short8*)lds_w;
#pragma unroll
  for (int ks = 0; ks < 4; ++ks){
#pragma unroll
    for (int ct = 0; ct < 8; ++ct){
      short8 bs = lw[((0 * 4 + ks) * 8 + ct) * 64 + lane];
      short8 bn = lw[((1 * 4 + ks) * 8 + ct) * 64 + lane];
#pragma unroll
      for (int rt = 0; rt < 2; ++rt){
        acc[rt][ct] = __builtin_amdgcn_mfma_f32_16x16x32_bf16(a_s[rt][ks], bs, acc[rt][ct], 0, 0, 0);
        acc[rt][ct] = __builtin_amdgcn_mfma_f32_16x16x32_bf16(a_n[rt][ks], bn, acc[rt][ct], 0, 0, 0);
      }
    }
  }

  // epilogue: bf16 Y store (C layout: col=lane&15, row=quad*4+reg) + per-wave LDS stats
  float* wred = lds_red + wave * 256;
#pragma unroll
  for (int rt = 0; rt < 2; ++rt){
    int rowq = row0 + rt * 16 + quad * 4;
#pragma unroll
    for (int ct = 0; ct < 8; ++ct){
      int col = ct * 16 + l15;
      float s = 0.f, q = 0.f;
#pragma unroll
      for (int rg = 0; rg < 4; ++rg){
        float yv = acc[rt][ct][rg];
        Yb[(size_t)(rowq + rg) * 128 + col] = f2bf(yv);
        s += yv; q += yv * yv;
      }
      s += __shfl_xor(s, 16); s += __shfl_xor(s, 32);
      q += __shfl_xor(q, 16); q += __shfl_xor(q, 32);
      if (lane < 16){
        if (rt == 0) wred[ct * 16 + lane] = s; else wred[ct * 16 + lane] += s;
      } else if (lane < 32){
        int c2 = ct * 16 + (lane & 15);
        if (rt == 0) wred[128 + c2] = q; else wred[128 + c2] += q;
      }
    }
  }
  __syncthreads();
  // cross-wave reduce -> 256 global atomics per block
  {
    float tot = lds_red[tid] + lds_red[256 + tid] + lds_red[512 + tid] + lds_red[768 + tid];
    int col = tid & 127;
    int slot = blockIdx.x & 63;
    float* dstp = (tid < 128) ? (stats + slot * 128 + col)
                              : (stats + 64 * 128 + slot * 128 + col);
    atomicAdd(dstp, tot);
  }
}

// ---- reduce stats -> scale/shift (8 independent accumulators for MLP) ----
__global__ __launch_bounds__(128) void finalize_k(const float* __restrict__ stats,
                                                  const float* __restrict__ gamma,
                                                  const float* __restrict__ beta,
                                                  float* __restrict__ scsh){
  int d = threadIdx.x;
  float s0=0.f,s1=0.f,s2=0.f,s3=0.f,q0=0.f,q1=0.f,q2=0.f,q3=0.f;
  for (int k = 0; k < 64; k += 4){
    s0 += stats[(k+0) * 128 + d];
    s1 += stats[(k+1) * 128 + d];
    s2 += stats[(k+2) * 128 + d];
    s3 += stats[(k+3) * 128 + d];
    q0 += stats[64*128 + (k+0) * 128 + d];
    q1 += stats[64*128 + (k+1) * 128 + d];
    q2 += stats[64*128 + (k+2) * 128 + d];
    q3 += stats[64*128 + (k+3) * 128 + d];
  }
  float s = (s0+s1)+(s2+s3);
  float q = (q0+q1)+(q2+q3);
  float inv = 1.0f / (float)M_;
  float mean = s * inv;
  float var  = q * inv - mean * mean;
  float rstd = rsqrtf(var + 1e-5f);
  float scale = gamma[d] * rstd;
  scsh[d]       = scale;
  scsh[128 + d] = beta[d] - mean * scale;
}

// ---- mid-layer BN apply + ReLU: Y bf16 -> X1 bf16 (both [v][n][d], pure stream) ----
__global__ __launch_bounds__(256) void bn_mid_k(const uint4* __restrict__ Y,
                                                const float* __restrict__ scsh,
                                                uint4* __restrict__ Xo){
  int i = blockIdx.x * 256 + threadIdx.x;          // 8 elems
  int c = (i * 8) & 127;
  uint4 y = Y[i];
  float4 sc0 = *(const float4*)(scsh + c);
  float4 sc1 = *(const float4*)(scsh + c + 4);
  float4 sh0 = *(const float4*)(scsh + 128 + c);
  float4 sh1 = *(const float4*)(scsh + 132 + c);
  float x0 = fmaxf(0.f, bf2f((unsigned short)(y.x & 0xffff)) * sc0.x + sh0.x);
  float x1 = fmaxf(0.f, bf2f((unsigned short)(y.x >> 16))    * sc0.y + sh0.y);
  float x2 = fmaxf(0.f, bf2f((unsigned short)(y.y & 0xffff)) * sc0.z + sh0.z);
  float x3 = fmaxf(0.f, bf2f((unsigned short)(y.y >> 16))    * sc0.w + sh0.w);
  float x4 = fmaxf(0.f, bf2f((unsigned short)(y.z & 0xffff)) * sc1.x + sh1.x);
  float x5 = fmaxf(0.f, bf2f((unsigned short)(y.z >> 16))    * sc1.y + sh1.y);
  float x6 = fmaxf(0.f, bf2f((unsigned short)(y.w & 0xffff)) * sc1.z + sh1.z);
  float x7 = fmaxf(0.f, bf2f((unsigned short)(y.w >> 16))    * sc1.w + sh1.w);
  uint4 o;
  o.x = pack2(x0, x1);
  o.y = pack2(x2, x3);
  o.z = pack2(x4, x5);
  o.w = pack2(x6, x7);
  Xo[i] = o;
}

// ---- final BN apply + ReLU: Y [v][n][d] bf16 -> out [n][v][d] fp32 (transpose back) ----
__global__ __launch_bounds__(256) void bn_out_k(const uint4* __restrict__ Y,
                                                const float* __restrict__ scsh,
                                                float4* __restrict__ out){
  int v = blockIdx.x;
  int t = threadIdx.x;
  int n = t >> 4, dc = t & 15;
  uint4 y = Y[(size_t)v * 256 + t];
  int d0 = dc * 8;
  float4 sc0 = *(const float4*)(scsh + d0);
  float4 sc1 = *(const float4*)(scsh + d0 + 4);
  float4 sh0 = *(const float4*)(scsh + 128 + d0);
  float4 sh1 = *(const float4*)(scsh + 128 + d0 + 4);
  float4 o0, o1;
  o0.x = fmaxf(0.f, bf2f((unsigned short)(y.x & 0xffff)) * sc0.x + sh0.x);
  o0.y = fmaxf(0.f, bf2f((unsigned short)(y.x >> 16))    * sc0.y + sh0.y);
  o0.z = fmaxf(0.f, bf2f((unsigned short)(y.y & 0xffff)) * sc0.z + sh0.z);
  o0.w = fmaxf(0.f, bf2f((unsigned short)(y.y >> 16))    * sc0.w + sh0.w);
  o1.x = fmaxf(0.f, bf2f((unsigned short)(y.z & 0xffff)) * sc1.x + sh1.x);
  o1.y = fmaxf(0.f, bf2f((unsigned short)(y.z >> 16))    * sc1.y + sh1.y);
  o1.z = fmaxf(0.f, bf2f((unsigned short)(y.w & 0xffff)) * sc1.z + sh1.z);
  o1.w = fmaxf(0.f, bf2f((unsigned short)(y.w >> 16))    * sc1.w + sh1.w);
  size_t ob = ((size_t)n * V_ + v) * 32 + (size_t)dc * 2;
  out[ob]     = o0;
  out[ob + 1] = o1;
}

static inline size_t align_up(size_t x, size_t a){ return (x + a - 1) & ~(a - 1); }

extern "C" void kernel_launch(void* const* d_in, const int* in_sizes, int n_in,
                              void* d_out, int out_size, void* d_ws, size_t ws_size,
                              hipStream_t stream){
  const float* H     = (const float*)d_in[0];
  const int*   esrc  = (const int*)  d_in[1];
  const int*   edst  = (const int*)  d_in[2];
  const float* avals = (const float*)d_in[3];
  const float* Wself = (const float*)d_in[4];
  const float* Wnei  = (const float*)d_in[5];
  const float* gamma = (const float*)d_in[6];
  const float* beta  = (const float*)d_in[7];

  char* ws = (char*)d_ws;
  size_t off = 0;
  unsigned short* Xb   = (unsigned short*)(ws + off); off += align_up((size_t)M_ * D_ * 2, 256);
  unsigned short* Y0   = (unsigned short*)(ws + off); off += align_up((size_t)M_ * D_ * 2, 256);
  unsigned short* X1   = (unsigned short*)(ws + off); off += align_up((size_t)M_ * D_ * 2, 256);
  unsigned short* Wb   = (unsigned short*)(ws + off); off += align_up((size_t)L_ * 2 * D_ * D_ * 2, 256);
  int*   row_ptr = (int*)  (ws + off); off += align_up((size_t)(V_ + 1) * 4, 256);
  int*   csr_col = (int*)  (ws + off); off += align_up((size_t)E_ * 4, 256);
  float* csr_val = (float*)(ws + off); off += align_up((size_t)E_ * 4, 256);
  float* scsh0   = (float*)(ws + off); off += align_up((size_t)2 * 128 * 4, 256);
  float* scsh1   = (float*)(ws + off); off += align_up((size_t)2 * 128 * 4, 256);
  // contiguous zeroed region: cnt | fill | stats0 | stats1
  char* zbase = ws + off;
  int*   cnt    = (int*)  (ws + off); off += (size_t)V_ * 4;
  int*   fill   = (int*)  (ws + off); off += (size_t)V_ * 4;
  float* stats0 = (float*)(ws + off); off += (size_t)64 * 128 * 2 * 4;
  float* stats1 = (float*)(ws + off); off += (size_t)64 * 128 * 2 * 4;
  size_t zbytes = (size_t)(ws + off - zbase);
  unsigned short* Y1 = Xb;   // Xb is dead after gemm0 reads it
  (void)ws_size; (void)in_sizes; (void)n_in; (void)out_size;

  conv_in_k<<<V_, 256, 0, stream>>>(H, Xb);
  conv_w_k<<<8192 / 256, 256, 0, stream>>>(Wself, Wnei, Wb);
  hipMemsetAsync(zbase, 0, zbytes, stream);
  hist_k<<<E_ / 256, 256, 0, stream>>>(edst, cnt);
  scan_k<<<1, 256, 0, stream>>>(cnt, row_ptr);
  scatter_k<<<E_ / 256, 256, 0, stream>>>(esrc, edst, avals, row_ptr, fill, csr_col, csr_val);

  // ---- layer 0 (SpMM fused into GEMM) ----
  gemm_k<<<M_ / 128, 256, 0, stream>>>(Xb, (const uint4*)Wb,
                                       row_ptr, csr_col, csr_val, Y0, stats0);
  finalize_k<<<1, 128, 0, stream>>>(stats0, gamma, beta, scsh0);

  // ---- BN+ReLU of layer 0 (streaming pass) ----
  bn_mid_k<<<M_ * D_ / 8 / 256, 256, 0, stream>>>((const uint4*)Y0, scsh0, (uint4*)X1);

  // ---- layer 1 ----
  gemm_k<<<M_ / 128, 256, 0, stream>>>(X1, (const uint4*)Wb + 4096,
                                       row_ptr, csr_col, csr_val, Y1, stats1);
  finalize_k<<<1, 128, 0, stream>>>(stats1, gamma + 128, beta + 128, scsh1);
  bn_out_k<<<V_, 256, 0, stream>>>((const uint4*)Y1, scsh1, (float4*)d_out);
}

// Round 6
// 460.006 us; speedup vs baseline: 1.2773x; 1.0874x over previous
//
#include <hip/hip_runtime.h>

#define N_ 16
#define V_ 16384
#define D_ 128
#define E_ 65536
#define L_ 2
#define M_ (N_*V_)   // 262144 rows

// Working layout for X/Y is [v][n][d] (v-major): row r = v*16+n of a row-major [M][128]
// matrix. gemm_k: 512-thread blocks, 8 waves, each wave owns ONE vertex (16 rows).
// SpMM is fused: each wave gathers its vertex's neighbor rows with an edge-outer,
// 2-deep software-pipelined loop (next edge's 4x16B loads issued before current FMAs)
// into f32 regs shaped like MFMA A-fragments. 64KB weight slab in LDS is shared by all
// 8 waves -> 2 blocks/CU = 16 waves/CU (2x round-4 occupancy at halved VGPR pressure).
// BN+ReLU between layers stays a separate streaming pass (bn_mid_k).

typedef __attribute__((ext_vector_type(8))) short short8;
typedef __attribute__((ext_vector_type(4))) float floatx4;

__device__ inline unsigned short f2bf(float x){
  unsigned u = __builtin_bit_cast(unsigned, x);
  unsigned r = u + 0x7fffu + ((u >> 16) & 1u);
  return (unsigned short)(r >> 16);
}
__device__ inline float bf2f(unsigned short h){
  unsigned u = ((unsigned)h) << 16;
  return __builtin_bit_cast(float, u);
}
__device__ inline unsigned pack2(float a, float b){
  return (unsigned)f2bf(a) | ((unsigned)f2bf(b) << 16);
}

// ---- H [n][v][d] fp32 -> Xb [v][n][d] bf16 (transpose fused into convert) ----
__global__ __launch_bounds__(256) void conv_in_k(const float* __restrict__ H,
                                                 unsigned short* __restrict__ Xb){
  int v = blockIdx.x;
  int t = threadIdx.x;
  int n = t >> 4, dc = t & 15;            // dc: which 8-elem chunk of d
  const float4* h4 = (const float4*)H;
  size_t base = ((size_t)n * V_ + v) * 32 + (size_t)dc * 2;
  float4 a = h4[base], b = h4[base + 1];
  uint4 o;
  o.x = pack2(a.x, a.y);
  o.y = pack2(a.z, a.w);
  o.z = pack2(b.x, b.y);
  o.w = pack2(b.z, b.w);
  ((uint4*)Xb)[(size_t)v * 256 + t] = o;  // contiguous 4KB per v
}

// ---- weights fp32 -> bf16 in MFMA frag-major layout [l][mat][ks][ct][lane][8] ----
__global__ __launch_bounds__(256) void conv_w_k(const float* __restrict__ Wself,
                                                const float* __restrict__ Wnei,
                                                unsigned short* __restrict__ Wb){
  int f = blockIdx.x * 256 + threadIdx.x;          // 0..8191 frags
  int lane = f & 63;
  int ct   = (f >> 6) & 7;
  int ks   = (f >> 9) & 3;
  int mat  = (f >> 11) & 1;
  int l    = (f >> 12) & 1;
  int e = ct * 16 + (lane & 15);
  int d = ks * 32 + (lane >> 4) * 8;
  const float* src = (mat ? Wnei : Wself) + ((size_t)l * D_ * D_ + e * D_ + d);
  uint4 o;
  o.x = pack2(src[0], src[1]);
  o.y = pack2(src[2], src[3]);
  o.z = pack2(src[4], src[5]);
  o.w = pack2(src[6], src[7]);
  ((uint4*)Wb)[f] = o;
}

// ---- CSR build ----
__global__ __launch_bounds__(256) void hist_k(const int* __restrict__ dst, int* __restrict__ cnt){
  int e = blockIdx.x * 256 + threadIdx.x;
  atomicAdd(&cnt[dst[e]], 1);
}

__global__ __launch_bounds__(256) void scan_k(const int* __restrict__ cnt, int* __restrict__ row_ptr){
  __shared__ int part[256];
  int t = threadIdx.x;
  int base = t * 64;
  int s = 0;
  for (int i = 0; i < 64; ++i) s += cnt[base + i];
  part[t] = s;
  __syncthreads();
  for (int d = 1; d < 256; d <<= 1){
    int v = (t >= d) ? part[t - d] : 0;
    __syncthreads();
    part[t] += v;
    __syncthreads();
  }
  int off = part[t] - s;   // exclusive prefix
  for (int i = 0; i < 64; ++i){
    row_ptr[base + i] = off;
    off += cnt[base + i];
  }
  if (t == 255) row_ptr[V_] = off;
}

__global__ __launch_bounds__(256) void scatter_k(const int* __restrict__ src,
                                                 const int* __restrict__ dst,
                                                 const float* __restrict__ vals,
                                                 const int* __restrict__ row_ptr,
                                                 int* __restrict__ fill,
                                                 int* __restrict__ csr_col,
                                                 float* __restrict__ csr_val){
  int e = blockIdx.x * 256 + threadIdx.x;
  int d = dst[e];
  int pos = row_ptr[d] + atomicAdd(&fill[d], 1);
  csr_col[pos] = src[e];
  csr_val[pos] = vals[e];
}

// ---- Fused SpMM + GEMM (no NORM): Y = X*Ws^T + (A @ X)*Wn^T (bf16 MFMA)
//      512 threads = 8 waves, 1 vertex/wave, 8 vertices (128 rows) per block.
//      -> Y bf16 + fused BN partial stats (LDS-reduced, 256 atomics/block). ----
__global__ __launch_bounds__(512, 4) void gemm_k(const unsigned short* __restrict__ X,
                                                 const uint4* __restrict__ Wfrag,
                                                 const int* __restrict__ row_ptr,
                                                 const int* __restrict__ csr_col,
                                                 const float* __restrict__ csr_val,
                                                 unsigned short* __restrict__ Yb,
                                                 float* __restrict__ stats){
  __shared__ uint4 lds_w[4096];                     // 64 KB: [mat][ks][ct][lane]
  __shared__ float lds_red[8 * 256];                // 8 KB per-wave stats slab
  int tid = threadIdx.x;
  for (int i = tid; i < 4096; i += 512) lds_w[i] = Wfrag[i];   // barrier deferred to post-gather

  int wave = tid >> 6, lane = tid & 63;
  int quad = lane >> 4, l15 = lane & 15;
  int v = blockIdx.x * 8 + wave;                    // wave owns ONE vertex
  int row0 = v * 16;

  // hoist self-row A-frags (4 independent loads, in flight during gather)
  short8 a_s[4];
#pragma unroll
  for (int ks = 0; ks < 4; ++ks)
    a_s[ks] = *(const short8*)(X + (size_t)(row0 + l15) * 128 + ks * 32 + quad * 8);

  int r0 = row_ptr[v], r1 = row_ptr[v + 1];

  // ---- fused gather, edge-outer, 2-deep pipelined ----
  float accn[4][8];
#pragma unroll
  for (int ks = 0; ks < 4; ++ks)
#pragma unroll
    for (int j = 0; j < 8; ++j) accn[ks][j] = 0.f;

  if (r0 < r1){
    int c = csr_col[r0];
    float a = csr_val[r0];
    const unsigned short* rp = X + ((size_t)c * 16 + l15) * 128 + quad * 8;
    short8 w0 = *(const short8*)(rp);
    short8 w1 = *(const short8*)(rp + 32);
    short8 w2 = *(const short8*)(rp + 64);
    short8 w3 = *(const short8*)(rp + 96);
    for (int i = r0; i < r1; ++i){
      int ip = (i + 1 < r1) ? i + 1 : i;
      int cn = csr_col[ip];
      float an = csr_val[ip];
      const unsigned short* rpn = X + ((size_t)cn * 16 + l15) * 128 + quad * 8;
      short8 n0 = *(const short8*)(rpn);          // next-edge loads issued BEFORE
      short8 n1 = *(const short8*)(rpn + 32);     // current-edge FMAs
      short8 n2 = *(const short8*)(rpn + 64);
      short8 n3 = *(const short8*)(rpn + 96);
#pragma unroll
      for (int j = 0; j < 8; ++j) accn[0][j] += a * bf2f((unsigned short)w0[j]);
#pragma unroll
      for (int j = 0; j < 8; ++j) accn[1][j] += a * bf2f((unsigned short)w1[j]);
#pragma unroll
      for (int j = 0; j < 8; ++j) accn[2][j] += a * bf2f((unsigned short)w2[j]);
#pragma unroll
      for (int j = 0; j < 8; ++j) accn[3][j] += a * bf2f((unsigned short)w3[j]);
      w0 = n0; w1 = n1; w2 = n2; w3 = n3;
      a = an;
    }
  }
  // convert to bf16 A-frags (same per-(ks,j) edge-order summation as before)
  short8 a_n[4];
#pragma unroll
  for (int ks = 0; ks < 4; ++ks)
#pragma unroll
    for (int j = 0; j < 8; ++j) a_n[ks][j] = (short)f2bf(accn[ks][j]);

  __syncthreads();                                  // weights staged (overlapped with gather)

  floatx4 zero = {0.f, 0.f, 0.f, 0.f};
  floatx4 acc[8];
#pragma unroll
  for (int ct = 0; ct < 8; ++ct) acc[ct] = zero;

  const short8* lw = (const short8*)lds_w;
#pragma unroll
  for (int ks = 0; ks < 4; ++ks){
#pragma unroll
    for (int ct = 0; ct < 8; ++ct){
      short8 bs = lw[((0 * 4 + ks) * 8 + ct) * 64 + lane];
      short8 bn = lw[((1 * 4 + ks) * 8 + ct) * 64 + lane];
      acc[ct] = __builtin_amdgcn_mfma_f32_16x16x32_bf16(a_s[ks], bs, acc[ct], 0, 0, 0);
      acc[ct] = __builtin_amdgcn_mfma_f32_16x16x32_bf16(a_n[ks], bn, acc[ct], 0, 0, 0);
    }
  }

  // epilogue: bf16 Y store (C layout: col=lane&15, row=quad*4+reg) + per-wave LDS stats
  float* wred = lds_red + wave * 256;
  int rowq = row0 + quad * 4;
#pragma unroll
  for (int ct = 0; ct < 8; ++ct){
    int col = ct * 16 + l15;
    float s = 0.f, q = 0.f;
#pragma unroll
    for (int rg = 0; rg < 4; ++rg){
      float yv = acc[ct][rg];
      Yb[(size_t)(rowq + rg) * 128 + col] = f2bf(yv);
      s += yv; q += yv * yv;
    }
    s += __shfl_xor(s, 16); s += __shfl_xor(s, 32);
    q += __shfl_xor(q, 16); q += __shfl_xor(q, 32);
    if (lane < 16)      wred[ct * 16 + lane] = s;
    else if (lane < 32) wred[128 + ct * 16 + (lane & 15)] = q;
  }
  __syncthreads();
  // cross-wave reduce -> 256 global atomics per block
  if (tid < 256){
    float tot = 0.f;
#pragma unroll
    for (int w = 0; w < 8; ++w) tot += lds_red[w * 256 + tid];
    int col = tid & 127;
    int slot = blockIdx.x & 63;
    float* dstp = (tid < 128) ? (stats + slot * 128 + col)
                              : (stats + 64 * 128 + slot * 128 + col);
    atomicAdd(dstp, tot);
  }
}

// ---- reduce stats -> scale/shift (independent accumulators for MLP) ----
__global__ __launch_bounds__(128) void finalize_k(const float* __restrict__ stats,
                                                  const float* __restrict__ gamma,
                                                  const float* __restrict__ beta,
                                                  float* __restrict__ scsh){
  int d = threadIdx.x;
  float s0=0.f,s1=0.f,s2=0.f,s3=0.f,q0=0.f,q1=0.f,q2=0.f,q3=0.f;
  for (int k = 0; k < 64; k += 4){
    s0 += stats[(k+0) * 128 + d];
    s1 += stats[(k+1) * 128 + d];
    s2 += stats[(k+2) * 128 + d];
    s3 += stats[(k+3) * 128 + d];
    q0 += stats[64*128 + (k+0) * 128 + d];
    q1 += stats[64*128 + (k+1) * 128 + d];
    q2 += stats[64*128 + (k+2) * 128 + d];
    q3 += stats[64*128 + (k+3) * 128 + d];
  }
  float s = (s0+s1)+(s2+s3);
  float q = (q0+q1)+(q2+q3);
  float inv = 1.0f / (float)M_;
  float mean = s * inv;
  float var  = q * inv - mean * mean;
  float rstd = rsqrtf(var + 1e-5f);
  float scale = gamma[d] * rstd;
  scsh[d]       = scale;
  scsh[128 + d] = beta[d] - mean * scale;
}

// ---- mid-layer BN apply + ReLU: Y bf16 -> X1 bf16 (both [v][n][d], pure stream) ----
__global__ __launch_bounds__(256) void bn_mid_k(const uint4* __restrict__ Y,
                                                const float* __restrict__ scsh,
                                                uint4* __restrict__ Xo){
  int i = blockIdx.x * 256 + threadIdx.x;          // 8 elems
  int c = (i * 8) & 127;
  uint4 y = Y[i];
  float4 sc0 = *(const float4*)(scsh + c);
  float4 sc1 = *(const float4*)(scsh + c + 4);
  float4 sh0 = *(const float4*)(scsh + 128 + c);
  float4 sh1 = *(const float4*)(scsh + 132 + c);
  float x0 = fmaxf(0.f, bf2f((unsigned short)(y.x & 0xffff)) * sc0.x + sh0.x);
  float x1 = fmaxf(0.f, bf2f((unsigned short)(y.x >> 16))    * sc0.y + sh0.y);
  float x2 = fmaxf(0.f, bf2f((unsigned short)(y.y & 0xffff)) * sc0.z + sh0.z);
  float x3 = fmaxf(0.f, bf2f((unsigned short)(y.y >> 16))    * sc0.w + sh0.w);
  float x4 = fmaxf(0.f, bf2f((unsigned short)(y.z & 0xffff)) * sc1.x + sh1.x);
  float x5 = fmaxf(0.f, bf2f((unsigned short)(y.z >> 16))    * sc1.y + sh1.y);
  float x6 = fmaxf(0.f, bf2f((unsigned short)(y.w & 0xffff)) * sc1.z + sh1.z);
  float x7 = fmaxf(0.f, bf2f((unsigned short)(y.w >> 16))    * sc1.w + sh1.w);
  uint4 o;
  o.x = pack2(x0, x1);
  o.y = pack2(x2, x3);
  o.z = pack2(x4, x5);
  o.w = pack2(x6, x7);
  Xo[i] = o;
}

// ---- final BN apply + ReLU: Y [v][n][d] bf16 -> out [n][v][d] fp32 (transpose back) ----
__global__ __launch_bounds__(256) void bn_out_k(const uint4* __restrict__ Y,
                                                const float* __restrict__ scsh,
                                                float4* __restrict__ out){
  int v = blockIdx.x;
  int t = threadIdx.x;
  int n = t >> 4, dc = t & 15;
  uint4 y = Y[(size_t)v * 256 + t];
  int d0 = dc * 8;
  float4 sc0 = *(const float4*)(scsh + d0);
  float4 sc1 = *(const float4*)(scsh + d0 + 4);
  float4 sh0 = *(const float4*)(scsh + 128 + d0);
  float4 sh1 = *(const float4*)(scsh + 128 + d0 + 4);
  float4 o0, o1;
  o0.x = fmaxf(0.f, bf2f((unsigned short)(y.x & 0xffff)) * sc0.x + sh0.x);
  o0.y = fmaxf(0.f, bf2f((unsigned short)(y.x >> 16))    * sc0.y + sh0.y);
  o0.z = fmaxf(0.f, bf2f((unsigned short)(y.y & 0xffff)) * sc0.z + sh0.z);
  o0.w = fmaxf(0.f, bf2f((unsigned short)(y.y >> 16))    * sc0.w + sh0.w);
  o1.x = fmaxf(0.f, bf2f((unsigned short)(y.z & 0xffff)) * sc1.x + sh1.x);
  o1.y = fmaxf(0.f, bf2f((unsigned short)(y.z >> 16))    * sc1.y + sh1.y);
  o1.z = fmaxf(0.f, bf2f((unsigned short)(y.w & 0xffff)) * sc1.z + sh1.z);
  o1.w = fmaxf(0.f, bf2f((unsigned short)(y.w >> 16))    * sc1.w + sh1.w);
  size_t ob = ((size_t)n * V_ + v) * 32 + (size_t)dc * 2;
  out[ob]     = o0;
  out[ob + 1] = o1;
}

static inline size_t align_up(size_t x, size_t a){ return (x + a - 1) & ~(a - 1); }

extern "C" void kernel_launch(void* const* d_in, const int* in_sizes, int n_in,
                              void* d_out, int out_size, void* d_ws, size_t ws_size,
                              hipStream_t stream){
  const float* H     = (const float*)d_in[0];
  const int*   esrc  = (const int*)  d_in[1];
  const int*   edst  = (const int*)  d_in[2];
  const float* avals = (const float*)d_in[3];
  const float* Wself = (const float*)d_in[4];
  const float* Wnei  = (const float*)d_in[5];
  const float* gamma = (const float*)d_in[6];
  const float* beta  = (const float*)d_in[7];

  char* ws = (char*)d_ws;
  size_t off = 0;
  unsigned short* Xb   = (unsigned short*)(ws + off); off += align_up((size_t)M_ * D_ * 2, 256);
  unsigned short* Y0   = (unsigned short*)(ws + off); off += align_up((size_t)M_ * D_ * 2, 256);
  unsigned short* X1   = (unsigned short*)(ws + off); off += align_up((size_t)M_ * D_ * 2, 256);
  unsigned short* Wb   = (unsigned short*)(ws + off); off += align_up((size_t)L_ * 2 * D_ * D_ * 2, 256);
  int*   row_ptr = (int*)  (ws + off); off += align_up((size_t)(V_ + 1) * 4, 256);
  int*   csr_col = (int*)  (ws + off); off += align_up((size_t)E_ * 4, 256);
  float* csr_val = (float*)(ws + off); off += align_up((size_t)E_ * 4, 256);
  float* scsh0   = (float*)(ws + off); off += align_up((size_t)2 * 128 * 4, 256);
  float* scsh1   = (float*)(ws + off); off += align_up((size_t)2 * 128 * 4, 256);
  // contiguous zeroed region: cnt | fill | stats0 | stats1
  char* zbase = ws + off;
  int*   cnt    = (int*)  (ws + off); off += (size_t)V_ * 4;
  int*   fill   = (int*)  (ws + off); off += (size_t)V_ * 4;
  float* stats0 = (float*)(ws + off); off += (size_t)64 * 128 * 2 * 4;
  float* stats1 = (float*)(ws + off); off += (size_t)64 * 128 * 2 * 4;
  size_t zbytes = (size_t)(ws + off - zbase);
  unsigned short* Y1 = Xb;   // Xb is dead after gemm0 reads it
  (void)ws_size; (void)in_sizes; (void)n_in; (void)out_size;

  conv_in_k<<<V_, 256, 0, stream>>>(H, Xb);
  conv_w_k<<<8192 / 256, 256, 0, stream>>>(Wself, Wnei, Wb);
  hipMemsetAsync(zbase, 0, zbytes, stream);
  hist_k<<<E_ / 256, 256, 0, stream>>>(edst, cnt);
  scan_k<<<1, 256, 0, stream>>>(cnt, row_ptr);
  scatter_k<<<E_ / 256, 256, 0, stream>>>(esrc, edst, avals, row_ptr, fill, csr_col, csr_val);

  // ---- layer 0 (SpMM fused into GEMM) ----
  gemm_k<<<V_ / 8, 512, 0, stream>>>(Xb, (const uint4*)Wb,
                                     row_ptr, csr_col, csr_val, Y0, stats0);
  finalize_k<<<1, 128, 0, stream>>>(stats0, gamma, beta, scsh0);

  // ---- BN+ReLU of layer 0 (streaming pass) ----
  bn_mid_k<<<M_ * D_ / 8 / 256, 256, 0, stream>>>((const uint4*)Y0, scsh0, (uint4*)X1);

  // ---- layer 1 ----
  gemm_k<<<V_ / 8, 512, 0, stream>>>(X1, (const uint4*)Wb + 4096,
                                     row_ptr, csr_col, csr_val, Y1, stats1);
  finalize_k<<<1, 128, 0, stream>>>(stats1, gamma + 128, beta + 128, scsh1);
  bn_out_k<<<V_, 256, 0, stream>>>((const uint4*)Y1, scsh1, (float4*)d_out);
}